// Round 10
// baseline (156.212 us; speedup 1.0000x reference)
//
#include <hip/hip_runtime.h>
#include <math.h>

// Problem constants: B=8, C=256, CR=32, N=4096 (=64*64)
#define B_ 8
#define C_ 256
#define CR_ 32
#define N_ 4096
#define NH_ 8  // KV split factor (eighths)

typedef __attribute__((ext_vector_type(8))) short bf16x8;   // MFMA A/B frag
typedef __attribute__((ext_vector_type(4))) short bf16x4;
typedef __attribute__((ext_vector_type(4))) float f32x4;    // 16x16 C/D frag
typedef __attribute__((ext_vector_type(16))) float f32x16;  // 32x32 C/D frag
typedef __attribute__((ext_vector_type(2))) unsigned uint32x2;

#if defined(__has_builtin)
#if __has_builtin(__builtin_amdgcn_permlane32_swap)
#define HAVE_PLSWAP 1
#endif
#endif

__device__ inline short f2bf(float f) {  // RTNE
  union { float f; unsigned u; } v; v.f = f;
  unsigned r = v.u + 0x7FFFu + ((v.u >> 16) & 1u);
  return (short)(r >> 16);
}
__device__ inline float bf2f(short h) {
  union { unsigned u; float f; } v; v.u = ((unsigned)(unsigned short)h) << 16;
  return v.f;
}
__device__ inline short f2bf_r(float f) {  // cheap round for hot paths
  return (short)((__float_as_uint(f) + 0x8000u) >> 16);
}

// pack 2 f32 -> 1 dword of 2 bf16 (low=a, high=b), single VALU op
__device__ inline unsigned cvt_pk_bf16(float a, float b) {
  unsigned d;
  asm("v_cvt_pk_bf16_f32 %0, %1, %2" : "=v"(d) : "v"(a), "v"(b));
  return d;
}

// ---------------------------------------------------------------------------
// FRAGMENT-MAJOR LAYOUTS (round-5, kept).  All flash_attn hot loads are
// coalesced 1KB dwordx4: lane l reads base + l*16.
//   Kf[b][kt=0..127][ch=0..1][lane=0..63][e=0..7]  (A-frag: key=kt*32+(l&31),
//       c = ch*16 + (l>>5)*8 + e)
//   Qf[b][jt=0..127][ch=0..1][lane][e]             (B-frag: col=jt*32+(l&31),
//       c = ch*16 + (l>>5)*8 + e)
//   Vf[b][n16=0..255][lane][e]                     (A-frag: c=(l&31),
//       key = n16*16 + (l>>5)*8 + e)
// ROUND-10: consolidated model -- every unspilled structure = ~712 cyc/tile
// per SIMD vs ~200 issue-cycles of content: the serial S->exp2->pack->PV
// chain stalls and chains/SIMD never exceeded 4 unspilled.  R5's lean 1-jt
// body allocated 40 arch VGPR (~56 unified <= 64 = the 8-waves/SIMD class,
// m69), but its 4096-wave grid capped residency at 4/SIMD: occupancy was
// GRID-limited, not register-limited.  Fix: 2-wave blocks (128 thr, one
// j-tile per wave) x NH=8 -> 8192 waves in 4096 blocks = 8 waves/SIMD =
// 8 independent chains/SIMD.  NO launch-bounds min-wave coercion (3x
// lesson: it spills; natural allocation already fits the target class).
// Tripwire: WRITE_SIZE ~17.8 MB (OPart+LPart); growth = spill.
// ---------------------------------------------------------------------------

// ---------------------------------------------------------------------------
// Kernel 0: weight prep.  WtHi/WtLo = split-bf16 of Wt (log2e folded into Q
// rows 32..63 so softmax runs in exp2 domain).  WoB = bf16(Wo * scale).
// ---------------------------------------------------------------------------
__global__ __launch_bounds__(256) void prep_weights(const float* __restrict__ Wt,
                                                    const float* __restrict__ Wo,
                                                    const float* __restrict__ scale,
                                                    short* __restrict__ WtHi,
                                                    short* __restrict__ WtLo,
                                                    short* __restrict__ WoB) {
  const int blk = blockIdx.x, tid = threadIdx.x;
  if (blk < 96) {
    float v = Wt[blk * C_ + tid];
    if (blk >= 32 && blk < 64) v *= 1.44269504f;  // log2(e) into Q
    const short h = f2bf(v);
    WtHi[blk * C_ + tid] = h;
    WtLo[blk * C_ + tid] = f2bf(v - bf2f(h));
  } else {
    const int idx = (blk - 96) * 256 + tid;
    WoB[idx] = f2bf(Wo[idx] * scale[0]);
  }
}

// ---------------------------------------------------------------------------
// Kernel 1: QKV projection, pure MFMA, no LDS, x prefetched one chunk ahead.
// Epilogue writes directly into fragment-major Kf/Qf/Vf (scattered 2B
// stores, paid once here instead of on every flash_attn fragment load).
// ---------------------------------------------------------------------------
__global__ __launch_bounds__(256) void qkv_mfma(const float* __restrict__ x,
                                                const short* __restrict__ WtHi,
                                                const short* __restrict__ WtLo,
                                                short* __restrict__ Kf,
                                                short* __restrict__ Qf,
                                                short* __restrict__ Vf) {
  const int b = blockIdx.y;
  const int tid = threadIdx.x;
  const int wave = tid >> 6, lane = tid & 63;
  const int col = lane & 15, quad = lane >> 4;
  const int n0 = (blockIdx.x * 4 + wave) * 16;

  const f32x4 z4 = {0.f, 0.f, 0.f, 0.f};
  f32x4 acc[6] = {z4, z4, z4, z4, z4, z4};  // 0..3 = KQ o-tiles, 4..5 = V

  const float* xb = x + (size_t)b * C_ * N_ + n0 + col;
  float xcur[8], xnxt[8];
#pragma unroll
  for (int j = 0; j < 8; ++j) xcur[j] = xb[(size_t)(quad * 8 + j) * N_];

#pragma unroll 2
  for (int c0 = 0; c0 < C_; c0 += 32) {
    if (c0 < C_ - 32) {
#pragma unroll
      for (int j = 0; j < 8; ++j)
        xnxt[j] = xb[(size_t)(c0 + 32 + quad * 8 + j) * N_];
    }
    bf16x8 xh, xl;
#pragma unroll
    for (int j = 0; j < 8; ++j) {
      const short h = (short)(__float_as_uint(xcur[j]) >> 16);  // trunc hi
      xh[j] = h;
      xl[j] = f2bf_r(xcur[j] - bf2f(h));
    }
#pragma unroll
    for (int ot = 0; ot < 4; ++ot) {  // K/Q: B-operand = Wt rows 0..63
      const int off = (ot * 16 + col) * C_ + c0 + quad * 8;
      const bf16x8 bh = *(const bf16x8*)(WtHi + off);
      const bf16x8 bl = *(const bf16x8*)(WtLo + off);
      acc[ot] = __builtin_amdgcn_mfma_f32_16x16x32_bf16(xh, bh, acc[ot], 0, 0, 0);
      acc[ot] = __builtin_amdgcn_mfma_f32_16x16x32_bf16(xl, bh, acc[ot], 0, 0, 0);
      acc[ot] = __builtin_amdgcn_mfma_f32_16x16x32_bf16(xh, bl, acc[ot], 0, 0, 0);
    }
#pragma unroll
    for (int ct = 0; ct < 2; ++ct) {  // V: A-operand = Wt rows 64..95
      const int off = ((64 + ct * 16) + col) * C_ + c0 + quad * 8;
      const bf16x8 ah = *(const bf16x8*)(WtHi + off);
      const bf16x8 al = *(const bf16x8*)(WtLo + off);
      acc[4 + ct] = __builtin_amdgcn_mfma_f32_16x16x32_bf16(ah, xh, acc[4 + ct], 0, 0, 0);
      acc[4 + ct] = __builtin_amdgcn_mfma_f32_16x16x32_bf16(ah, xl, acc[4 + ct], 0, 0, 0);
      acc[4 + ct] = __builtin_amdgcn_mfma_f32_16x16x32_bf16(al, xh, acc[4 + ct], 0, 0, 0);
    }
#pragma unroll
    for (int j = 0; j < 8; ++j) xcur[j] = xnxt[j];
  }

  // K epilogue (ot 0..1): D row=(quad*4+r)+n0 = key i, col-dim = c
#pragma unroll
  for (int ot = 0; ot < 2; ++ot)
#pragma unroll
    for (int r = 0; r < 4; ++r) {
      const int i = n0 + quad * 4 + r;
      const int c = ot * 16 + col;
      const int ln = (i & 31) | (((c >> 3) & 1) << 5);
      Kf[(((size_t)(b * 128 + (i >> 5)) * 2 + (c >> 4)) * 64 + ln) * 8 + (c & 7)] =
          f2bf(acc[ot][r]);
    }
  // Q epilogue (ot 2..3): col j = n, c = o-32
#pragma unroll
  for (int ot = 2; ot < 4; ++ot)
#pragma unroll
    for (int r = 0; r < 4; ++r) {
      const int j = n0 + quad * 4 + r;
      const int c = (ot - 2) * 16 + col;
      const int ln = (j & 31) | (((c >> 3) & 1) << 5);
      Qf[(((size_t)(b * 128 + (j >> 5)) * 2 + (c >> 4)) * 64 + ln) * 8 + (c & 7)] =
          f2bf(acc[ot][r]);
    }
  // V epilogue: c = ct*16+quad*4+r, key n = n0+col
#pragma unroll
  for (int ct = 0; ct < 2; ++ct)
#pragma unroll
    for (int r = 0; r < 4; ++r) {
      const int c = ct * 16 + quad * 4 + r;
      const int n = n0 + col;
      const int ln = c | (((n >> 3) & 1) << 5);
      Vf[((size_t)(b * 256 + (n >> 4)) * 64 + ln) * 8 + (n & 7)] =
          f2bf(acc[4 + ct][r]);
    }
}

// ---------------------------------------------------------------------------
// Kernel 2: 32x32-MFMA flash attention, zero LDS, fragment-major inputs.
// Block = 128 threads = 2 waves; EACH WAVE owns one 32-col j-tile x one
// KV-eighth (512 keys = 16 tiles of 32).  Grid (64 jp, 8 hq, 8 b) = 4096
// blocks = 8192 waves = 8 waves/SIMD (the lean 1-jt body allocates ~40
// arch VGPR, i.e. the <=64-unified 8-wave class).  8 independent
// S->exp2->pack->PV chains per SIMD to fill the ~70% stall fraction.
// K prefetched 1-deep; V loaded at tile start (self-covering ~250cyc to
// first use).  cvt_pk_bf16 pack (1 VALU/pair).  No waves/EU coercion.
// Tripwire: WRITE_SIZE ~17.8 MB; growth = spill.
// Last-iter K overread lands at most 1KB past the eighth: harmless (Kf/Qf
// are adjacent ws buffers).
// ---------------------------------------------------------------------------
__global__ __launch_bounds__(128) void flash_attn(const short* __restrict__ Kf,
                                                  const short* __restrict__ Qf,
                                                  const short* __restrict__ Vf,
                                                  short* __restrict__ OPart,
                                                  float* __restrict__ LPart) {
  const int b = blockIdx.z, hq = blockIdx.y;      // hq = KV eighth, 0..7
  const int tid = threadIdx.x;
  const int jt = blockIdx.x * 2 + (tid >> 6);     // j-tile 0..127, one per wave
  const int lane = tid & 63;
  const int j32 = lane & 31, h32 = lane >> 5;

  const f32x16 z16 = {0.f};
  // Q B-frags, loop-invariant, coalesced
  const short* pQ = Qf + ((size_t)(b * 128 + jt) * 2) * 512 + lane * 8;
  const bf16x8 qf0 = *(const bf16x8*)(pQ);
  const bf16x8 qf1 = *(const bf16x8*)(pQ + 512);

  const short* pK = Kf + ((size_t)(b * 128 + hq * 16) * 2) * 512 + lane * 8;
  const short* pV = Vf + ((size_t)(b * 256 + hq * 32)) * 512 + lane * 8;

  f32x16 acc = z16;
  float ps = 0.f;

  bf16x8 ka = *(const bf16x8*)(pK);
  bf16x8 kb = *(const bf16x8*)(pK + 512);

#pragma unroll 1
  for (int t = 0; t < 16; ++t) {
    // V for THIS tile: issued now, consumed after S+exp+pack (~250cyc)
    const bf16x8 va = *(const bf16x8*)(pV);
    const bf16x8 vb = *(const bf16x8*)(pV + 512);
    pK += 1024;
    pV += 1024;
    // K for NEXT tile (1-deep; last-iter overread harmless)
    const bf16x8 kan = *(const bf16x8*)(pK);
    const bf16x8 kbn = *(const bf16x8*)(pK + 512);

    // ---- S tile (32 i x 32 j), k=32 over two chunks ----
    __builtin_amdgcn_s_setprio(1);
    f32x16 s = __builtin_amdgcn_mfma_f32_32x32x16_bf16(ka, qf0, z16, 0, 0, 0);
    s = __builtin_amdgcn_mfma_f32_32x32x16_bf16(kb, qf1, s, 0, 0, 0);
    __builtin_amdgcn_s_setprio(0);
    // ---- p = exp2(s); l tree ----
    float p[16];
#pragma unroll
    for (int r = 0; r < 16; ++r) p[r] = __builtin_amdgcn_exp2f(s[r]);
    ps += (((p[0] + p[1]) + (p[2] + p[3])) + ((p[4] + p[5]) + (p[6] + p[7]))) +
          (((p[8] + p[9]) + (p[10] + p[11])) + ((p[12] + p[13]) + (p[14] + p[15])));
    // ---- pack row-pairs (cvt_pk: 1 VALU/pair) + permlane -> PV B-frags ----
    union { unsigned u[4]; bf16x8 v; } f0, f1;
#ifdef HAVE_PLSWAP
    {
      const unsigned d0 = cvt_pk_bf16(p[0], p[1]);
      const unsigned d1 = cvt_pk_bf16(p[2], p[3]);
      const unsigned d2 = cvt_pk_bf16(p[4], p[5]);
      const unsigned d3 = cvt_pk_bf16(p[6], p[7]);
      const uint32x2 r0 = __builtin_amdgcn_permlane32_swap(d0, d2, false, false);
      f0.u[0] = r0[0]; f0.u[2] = r0[1];
      const uint32x2 r1 = __builtin_amdgcn_permlane32_swap(d1, d3, false, false);
      f0.u[1] = r1[0]; f0.u[3] = r1[1];
      const unsigned d4 = cvt_pk_bf16(p[8], p[9]);
      const unsigned d5 = cvt_pk_bf16(p[10], p[11]);
      const unsigned d6 = cvt_pk_bf16(p[12], p[13]);
      const unsigned d7 = cvt_pk_bf16(p[14], p[15]);
      const uint32x2 r2 = __builtin_amdgcn_permlane32_swap(d4, d6, false, false);
      f1.u[0] = r2[0]; f1.u[2] = r2[1];
      const uint32x2 r3 = __builtin_amdgcn_permlane32_swap(d5, d7, false, false);
      f1.u[1] = r3[0]; f1.u[3] = r3[1];
    }
#else
    {
      unsigned d[8], xw[8];
#pragma unroll
      for (int k = 0; k < 8; ++k) d[k] = cvt_pk_bf16(p[2 * k], p[2 * k + 1]);
#pragma unroll
      for (int k = 0; k < 8; ++k) xw[k] = __shfl_xor((int)d[k], 32);
      f0.u[0] = h32 ? xw[2] : d[0];
      f0.u[1] = h32 ? xw[3] : d[1];
      f0.u[2] = h32 ? d[2] : xw[0];
      f0.u[3] = h32 ? d[3] : xw[1];
      f1.u[0] = h32 ? xw[6] : d[4];
      f1.u[1] = h32 ? xw[7] : d[5];
      f1.u[2] = h32 ? d[6] : xw[4];
      f1.u[3] = h32 ? d[7] : xw[5];
    }
#endif
    // ---- O += V @ P ----
    __builtin_amdgcn_s_setprio(1);
    acc = __builtin_amdgcn_mfma_f32_32x32x16_bf16(va, f0.v, acc, 0, 0, 0);
    acc = __builtin_amdgcn_mfma_f32_32x32x16_bf16(vb, f1.v, acc, 0, 0, 0);
    __builtin_amdgcn_s_setprio(0);

    ka = kan;
    kb = kbn;
  }

  // ---- epilogue: finish l across halves, write O/l partials ----
  const size_t base = ((size_t)b * NH_ + hq) * N_;
  const float l = ps + __shfl_xor(ps, 32);
  const int jg = jt * 32 + j32;
  if (h32 == 0) LPart[base + jg] = l;
  short* OP = OPart + (base + jg) * 32;
#pragma unroll
  for (int g = 0; g < 4; ++g) {  // regs 4g..4g+3 -> c = 8g + 4*h32 + 0..3
    bf16x4 o = {f2bf(acc[4 * g + 0]), f2bf(acc[4 * g + 1]),
                f2bf(acc[4 * g + 2]), f2bf(acc[4 * g + 3])};
    *(bf16x4*)(OP + 8 * g + 4 * h32) = o;
  }
}

// ---------------------------------------------------------------------------
// Kernel 3: merge 8 KV-eighth partials, normalize, out-proj, residual.
// Grid (64 n-blocks, 2 co-halves, 8 b) = 1024 blocks.
// out[b,co,n] = WoB @ (sum_h O_h / sum_h l_h) + x
// ---------------------------------------------------------------------------
__global__ __launch_bounds__(256) void out_proj(const short* __restrict__ OPart,
                                                const float* __restrict__ LPart,
                                                const short* __restrict__ WoB,
                                                const float* __restrict__ x,
                                                float* __restrict__ out) {
  const int b = blockIdx.z, chalf = blockIdx.y;
  const int tid = threadIdx.x;
  const int wave = tid >> 6, lane = tid & 63;
  const int col = lane & 15, quad = lane >> 4;
  const int jg = blockIdx.x * 64 + wave * 16 + col;  // global n/j
  const int n0 = blockIdx.x * 64 + wave * 16;

  float osum[8];
#pragma unroll
  for (int e = 0; e < 8; ++e) osum[e] = 0.f;
  float lsum = 0.f;
#pragma unroll
  for (int h = 0; h < NH_; ++h) {
    const size_t p = ((size_t)b * NH_ + h) * N_ + jg;
    const bf16x8 o = *(const bf16x8*)(OPart + p * 32 + quad * 8);
#pragma unroll
    for (int e = 0; e < 8; ++e) osum[e] += bf2f(o[e]);
    lsum += LPart[p];
  }
  const float linv = 1.f / lsum;
  bf16x8 bf;
#pragma unroll
  for (int e = 0; e < 8; ++e) bf[e] = f2bf(osum[e] * linv);

  const f32x4 z4 = {0.f, 0.f, 0.f, 0.f};
  const float* xb = x + (size_t)b * C_ * N_;
  float* ob = out + (size_t)b * C_ * N_;
#pragma unroll
  for (int ct = 0; ct < 8; ++ct) {
    const int ctg = chalf * 8 + ct;
    const bf16x8 af = *(const bf16x8*)(WoB + (ctg * 16 + col) * 32 + quad * 8);
    const f32x4 a = __builtin_amdgcn_mfma_f32_16x16x32_bf16(af, bf, z4, 0, 0, 0);
#pragma unroll
    for (int r = 0; r < 4; ++r) {
      const size_t idx = (size_t)(ctg * 16 + quad * 4 + r) * N_ + n0 + col;
      ob[idx] = a[r] + xb[idx];
    }
  }
}

// ---------------------------------------------------------------------------
extern "C" void kernel_launch(void* const* d_in, const int* in_sizes, int n_in,
                              void* d_out, int out_size, void* d_ws,
                              size_t ws_size, hipStream_t stream) {
  const float* x = (const float*)d_in[0];      // [8,256,64,64]
  const float* Wt = (const float*)d_in[1];     // [96,256]
  const float* Wo = (const float*)d_in[2];     // [256,32]
  const float* scale = (const float*)d_in[3];  // [1]
  float* out = (float*)d_out;

  // ws: OPart bf16 [8][8][4096][32] (16.8 MB) | LPart f32 [8][8][4096] (1 MB)
  //   | Kf (2 MB) | Qf (2 MB) | Vf (2 MB) | WtHi | WtLo | WoB  (~24 MB)
  short* OPart = (short*)d_ws;
  float* LPart = (float*)(OPart + (size_t)B_ * NH_ * N_ * 32);
  short* Kf = (short*)(LPart + (size_t)B_ * NH_ * N_);
  short* Qf = Kf + (size_t)B_ * 128 * 1024;
  short* Vf = Qf + (size_t)B_ * 128 * 1024;
  short* WtHi = Vf + (size_t)B_ * 256 * 512;
  short* WtLo = WtHi + 96 * C_;
  short* WoB = WtLo + 96 * C_;

  prep_weights<<<dim3(128), 256, 0, stream>>>(Wt, Wo, scale, WtHi, WtLo, WoB);
  qkv_mfma<<<dim3(64, B_), 256, 0, stream>>>(x, WtHi, WtLo, Kf, Qf, Vf);
  flash_attn<<<dim3(64, NH_, B_), 128, 0, stream>>>(Kf, Qf, Vf, OPart, LPart);
  out_proj<<<dim3(64, 2, B_), 256, 0, stream>>>(OPart, LPart, WoB, x, out);
}

// Round 11
// 150.707 us; speedup vs baseline: 1.0365x; 1.0365x over previous
//
#include <hip/hip_runtime.h>
#include <math.h>

// Problem constants: B=8, C=256, CR=32, N=4096 (=64*64)
#define B_ 8
#define C_ 256
#define CR_ 32
#define N_ 4096
#define NH_ 8  // KV split factor (eighths)

typedef __attribute__((ext_vector_type(8))) short bf16x8;   // MFMA A/B frag
typedef __attribute__((ext_vector_type(4))) short bf16x4;
typedef __attribute__((ext_vector_type(4))) float f32x4;    // 16x16 C/D frag
typedef __attribute__((ext_vector_type(16))) float f32x16;  // 32x32 C/D frag
typedef __attribute__((ext_vector_type(2))) unsigned uint32x2;

#if defined(__has_builtin)
#if __has_builtin(__builtin_amdgcn_permlane32_swap)
#define HAVE_PLSWAP 1
#endif
#endif

__device__ inline short f2bf(float f) {  // RTNE
  union { float f; unsigned u; } v; v.f = f;
  unsigned r = v.u + 0x7FFFu + ((v.u >> 16) & 1u);
  return (short)(r >> 16);
}
__device__ inline float bf2f(short h) {
  union { unsigned u; float f; } v; v.u = ((unsigned)(unsigned short)h) << 16;
  return v.f;
}
__device__ inline short f2bf_r(float f) {  // cheap round for hot paths
  return (short)((__float_as_uint(f) + 0x8000u) >> 16);
}

// pack 2 f32 -> 1 dword of 2 bf16 (low=a, high=b), single VALU op
__device__ inline unsigned cvt_pk_bf16(float a, float b) {
  unsigned d;
  asm("v_cvt_pk_bf16_f32 %0, %1, %2" : "=v"(d) : "v"(a), "v"(b));
  return d;
}

// ---------------------------------------------------------------------------
// FRAGMENT-MAJOR LAYOUTS (round-5, kept).
//   Kf[b][kt=0..127][ch=0..1][lane=0..63][e=0..7]  (A-frag: key=kt*32+(l&31),
//       c = ch*16 + (l>>5)*8 + e)
//   Qf[b][jt=0..127][ch=0..1][lane][e]             (B-frag: col=jt*32+(l&31),
//       c = ch*16 + (l>>5)*8 + e)
//   Vf[b][n16=0..255][lane][e]                     (A-frag: c=(l&31),
//       key = n16*16 + (l>>5)*8 + e)
// ROUND-11: flash is pinned at ~37-42us for 2/4/8 waves/SIMD and VALUBusy
// FELL as waves rose (40%@2w -> 26%@4w) -> not issue-bound; each wave is
// individually exposed to global-load latency (FETCH 24.8MB = 4x footprint
// -> frequent L2 misses ~600-900cyc vs ~200cyc per-tile issue window; 1-2
// deep register prefetch can't cover).  Fix: STAGE THE KV-EIGHTH IN LDS
// (64KB: K 32 + V 32) once per block; hot loop reads LDS only
// (ds_read_b128, conflict-free: fragment-major is linear lane*16B;
// ~120cyc latency covered by the existing 1-deep reg prefetch).  Block =
// 512 thr = 8 waves, one j-tile each, sharing the eighth -> K/V global
// traffic /8, LDS caps occupancy at 2 blocks/CU = 4 waves/SIMD (VGPR has
// huge slack to 128 unified -- no spill knife-edge, 3x lesson).
// Tripwire: WRITE_SIZE ~17.8MB; growth = spill.
// ---------------------------------------------------------------------------

// ---------------------------------------------------------------------------
// Kernel 0: weight prep.  WtHi/WtLo = split-bf16 of Wt (log2e folded into Q
// rows 32..63 so softmax runs in exp2 domain).  WoB = bf16(Wo * scale).
// ---------------------------------------------------------------------------
__global__ __launch_bounds__(256) void prep_weights(const float* __restrict__ Wt,
                                                    const float* __restrict__ Wo,
                                                    const float* __restrict__ scale,
                                                    short* __restrict__ WtHi,
                                                    short* __restrict__ WtLo,
                                                    short* __restrict__ WoB) {
  const int blk = blockIdx.x, tid = threadIdx.x;
  if (blk < 96) {
    float v = Wt[blk * C_ + tid];
    if (blk >= 32 && blk < 64) v *= 1.44269504f;  // log2(e) into Q
    const short h = f2bf(v);
    WtHi[blk * C_ + tid] = h;
    WtLo[blk * C_ + tid] = f2bf(v - bf2f(h));
  } else {
    const int idx = (blk - 96) * 256 + tid;
    WoB[idx] = f2bf(Wo[idx] * scale[0]);
  }
}

// ---------------------------------------------------------------------------
// Kernel 1: QKV projection, pure MFMA, no LDS, x prefetched one chunk ahead.
// Epilogue writes directly into fragment-major Kf/Qf/Vf (scattered 2B
// stores, paid once here instead of on every flash_attn fragment load).
// ---------------------------------------------------------------------------
__global__ __launch_bounds__(256) void qkv_mfma(const float* __restrict__ x,
                                                const short* __restrict__ WtHi,
                                                const short* __restrict__ WtLo,
                                                short* __restrict__ Kf,
                                                short* __restrict__ Qf,
                                                short* __restrict__ Vf) {
  const int b = blockIdx.y;
  const int tid = threadIdx.x;
  const int wave = tid >> 6, lane = tid & 63;
  const int col = lane & 15, quad = lane >> 4;
  const int n0 = (blockIdx.x * 4 + wave) * 16;

  const f32x4 z4 = {0.f, 0.f, 0.f, 0.f};
  f32x4 acc[6] = {z4, z4, z4, z4, z4, z4};  // 0..3 = KQ o-tiles, 4..5 = V

  const float* xb = x + (size_t)b * C_ * N_ + n0 + col;
  float xcur[8], xnxt[8];
#pragma unroll
  for (int j = 0; j < 8; ++j) xcur[j] = xb[(size_t)(quad * 8 + j) * N_];

#pragma unroll 2
  for (int c0 = 0; c0 < C_; c0 += 32) {
    if (c0 < C_ - 32) {
#pragma unroll
      for (int j = 0; j < 8; ++j)
        xnxt[j] = xb[(size_t)(c0 + 32 + quad * 8 + j) * N_];
    }
    bf16x8 xh, xl;
#pragma unroll
    for (int j = 0; j < 8; ++j) {
      const short h = (short)(__float_as_uint(xcur[j]) >> 16);  // trunc hi
      xh[j] = h;
      xl[j] = f2bf_r(xcur[j] - bf2f(h));
    }
#pragma unroll
    for (int ot = 0; ot < 4; ++ot) {  // K/Q: B-operand = Wt rows 0..63
      const int off = (ot * 16 + col) * C_ + c0 + quad * 8;
      const bf16x8 bh = *(const bf16x8*)(WtHi + off);
      const bf16x8 bl = *(const bf16x8*)(WtLo + off);
      acc[ot] = __builtin_amdgcn_mfma_f32_16x16x32_bf16(xh, bh, acc[ot], 0, 0, 0);
      acc[ot] = __builtin_amdgcn_mfma_f32_16x16x32_bf16(xl, bh, acc[ot], 0, 0, 0);
      acc[ot] = __builtin_amdgcn_mfma_f32_16x16x32_bf16(xh, bl, acc[ot], 0, 0, 0);
    }
#pragma unroll
    for (int ct = 0; ct < 2; ++ct) {  // V: A-operand = Wt rows 64..95
      const int off = ((64 + ct * 16) + col) * C_ + c0 + quad * 8;
      const bf16x8 ah = *(const bf16x8*)(WtHi + off);
      const bf16x8 al = *(const bf16x8*)(WtLo + off);
      acc[4 + ct] = __builtin_amdgcn_mfma_f32_16x16x32_bf16(ah, xh, acc[4 + ct], 0, 0, 0);
      acc[4 + ct] = __builtin_amdgcn_mfma_f32_16x16x32_bf16(ah, xl, acc[4 + ct], 0, 0, 0);
      acc[4 + ct] = __builtin_amdgcn_mfma_f32_16x16x32_bf16(al, xh, acc[4 + ct], 0, 0, 0);
    }
#pragma unroll
    for (int j = 0; j < 8; ++j) xcur[j] = xnxt[j];
  }

  // K epilogue (ot 0..1): D row=(quad*4+r)+n0 = key i, col-dim = c
#pragma unroll
  for (int ot = 0; ot < 2; ++ot)
#pragma unroll
    for (int r = 0; r < 4; ++r) {
      const int i = n0 + quad * 4 + r;
      const int c = ot * 16 + col;
      const int ln = (i & 31) | (((c >> 3) & 1) << 5);
      Kf[(((size_t)(b * 128 + (i >> 5)) * 2 + (c >> 4)) * 64 + ln) * 8 + (c & 7)] =
          f2bf(acc[ot][r]);
    }
  // Q epilogue (ot 2..3): col j = n, c = o-32
#pragma unroll
  for (int ot = 2; ot < 4; ++ot)
#pragma unroll
    for (int r = 0; r < 4; ++r) {
      const int j = n0 + quad * 4 + r;
      const int c = (ot - 2) * 16 + col;
      const int ln = (j & 31) | (((c >> 3) & 1) << 5);
      Qf[(((size_t)(b * 128 + (j >> 5)) * 2 + (c >> 4)) * 64 + ln) * 8 + (c & 7)] =
          f2bf(acc[ot][r]);
    }
  // V epilogue: c = ct*16+quad*4+r, key n = n0+col
#pragma unroll
  for (int ct = 0; ct < 2; ++ct)
#pragma unroll
    for (int r = 0; r < 4; ++r) {
      const int c = ct * 16 + quad * 4 + r;
      const int n = n0 + col;
      const int ln = c | (((n >> 3) & 1) << 5);
      Vf[((size_t)(b * 256 + (n >> 4)) * 64 + ln) * 8 + (n & 7)] =
          f2bf(acc[4 + ct][r]);
    }
}

// ---------------------------------------------------------------------------
// Kernel 2: 32x32-MFMA flash attention, LDS-staged K/V, fragment-major.
// Block = 512 threads = 8 waves; wave w owns j-tile jp*8+w; all waves share
// one KV-eighth staged in LDS (64 KB) ONCE before the loop.  Hot loop is
// LDS-only: 4x ds_read_b128/tile (linear lane*16 -> conflict-free) + the
// same S->exp2->cvt_pk->permlane->PV chain.  1-deep K reg prefetch covers
// the ~120cyc ds_read latency.  Linear grid 1024 with XCD-locality decode
// (8 (b,hq) groups per XCD -> staging reads stay L2-local).
// LDS 64KB -> 2 blocks/CU = 4 waves/SIMD; VGPR needs only <=128 unified.
// ---------------------------------------------------------------------------
__global__ __launch_bounds__(512) void flash_attn(const short* __restrict__ Kf,
                                                  const short* __restrict__ Qf,
                                                  const short* __restrict__ Vf,
                                                  short* __restrict__ OPart,
                                                  float* __restrict__ LPart) {
  __shared__ short Ks[16384];  // 16 k-tiles x 1024 shorts (2 KB) = 32 KB
  __shared__ short Vs[16384];  // 16 v-tiles x 1024 shorts = 32 KB

  const int bid = blockIdx.x;                 // 0..1023
  const int xcd = bid & 7, w = bid >> 3;      // w = 0..127
  const int g = xcd * 8 + (w >> 4);           // (b,hq) group 0..63, XCD-local
  const int b = g >> 3, hq = g & 7;
  const int jp = w & 15;                      // j-panel 0..15 (8 j-tiles)
  const int tid = threadIdx.x;
  const int wave = tid >> 6, lane = tid & 63;
  const int jt = jp * 8 + wave;               // this wave's j-tile 0..127
  const int j32 = lane & 31, h32 = lane >> 5;

  // ---- stage K/V eighth into LDS (coalesced 16B chunks, once) ----
  {
    const bf16x8* gK = (const bf16x8*)(Kf + ((size_t)(b * 128 + hq * 16) * 2) * 512);
    const bf16x8* gV = (const bf16x8*)(Vf + ((size_t)(b * 256 + hq * 32)) * 512);
    bf16x8* sK = (bf16x8*)Ks;
    bf16x8* sV = (bf16x8*)Vs;
#pragma unroll
    for (int i = 0; i < 4; ++i) {
      sK[tid + i * 512] = gK[tid + i * 512];
      sV[tid + i * 512] = gV[tid + i * 512];
    }
  }
  __syncthreads();

  const f32x16 z16 = {0.f};
  // Q B-frags, loop-invariant, coalesced from global
  const short* pQ = Qf + ((size_t)(b * 128 + jt) * 2) * 512 + lane * 8;
  const bf16x8 qf0 = *(const bf16x8*)(pQ);
  const bf16x8 qf1 = *(const bf16x8*)(pQ + 512);

  f32x16 acc = z16;
  float ps = 0.f;

  const short* sKl = Ks + lane * 8;
  const short* sVl = Vs + lane * 8;

  bf16x8 ka = *(const bf16x8*)(sKl);
  bf16x8 kb = *(const bf16x8*)(sKl + 512);

#pragma unroll 1
  for (int t = 0; t < 16; ++t) {
    // V for THIS tile (LDS, ~120cyc to first use after S+exp+pack)
    const bf16x8 va = *(const bf16x8*)(sVl + t * 1024);
    const bf16x8 vb = *(const bf16x8*)(sVl + t * 1024 + 512);
    // K for NEXT tile (1-deep; t=15 reads tile 15 again -- harmless)
    const int tn = (t + 1) & 15;
    const bf16x8 kan = *(const bf16x8*)(sKl + tn * 1024);
    const bf16x8 kbn = *(const bf16x8*)(sKl + tn * 1024 + 512);

    // ---- S tile (32 i x 32 j), k=32 over two chunks ----
    __builtin_amdgcn_s_setprio(1);
    f32x16 s = __builtin_amdgcn_mfma_f32_32x32x16_bf16(ka, qf0, z16, 0, 0, 0);
    s = __builtin_amdgcn_mfma_f32_32x32x16_bf16(kb, qf1, s, 0, 0, 0);
    __builtin_amdgcn_s_setprio(0);
    // ---- p = exp2(s); l tree ----
    float p[16];
#pragma unroll
    for (int r = 0; r < 16; ++r) p[r] = __builtin_amdgcn_exp2f(s[r]);
    ps += (((p[0] + p[1]) + (p[2] + p[3])) + ((p[4] + p[5]) + (p[6] + p[7]))) +
          (((p[8] + p[9]) + (p[10] + p[11])) + ((p[12] + p[13]) + (p[14] + p[15])));
    // ---- pack row-pairs (cvt_pk: 1 VALU/pair) + permlane -> PV B-frags ----
    union { unsigned u[4]; bf16x8 v; } f0, f1;
#ifdef HAVE_PLSWAP
    {
      const unsigned d0 = cvt_pk_bf16(p[0], p[1]);
      const unsigned d1 = cvt_pk_bf16(p[2], p[3]);
      const unsigned d2 = cvt_pk_bf16(p[4], p[5]);
      const unsigned d3 = cvt_pk_bf16(p[6], p[7]);
      const uint32x2 r0 = __builtin_amdgcn_permlane32_swap(d0, d2, false, false);
      f0.u[0] = r0[0]; f0.u[2] = r0[1];
      const uint32x2 r1 = __builtin_amdgcn_permlane32_swap(d1, d3, false, false);
      f0.u[1] = r1[0]; f0.u[3] = r1[1];
      const unsigned d4 = cvt_pk_bf16(p[8], p[9]);
      const unsigned d5 = cvt_pk_bf16(p[10], p[11]);
      const unsigned d6 = cvt_pk_bf16(p[12], p[13]);
      const unsigned d7 = cvt_pk_bf16(p[14], p[15]);
      const uint32x2 r2 = __builtin_amdgcn_permlane32_swap(d4, d6, false, false);
      f1.u[0] = r2[0]; f1.u[2] = r2[1];
      const uint32x2 r3 = __builtin_amdgcn_permlane32_swap(d5, d7, false, false);
      f1.u[1] = r3[0]; f1.u[3] = r3[1];
    }
#else
    {
      unsigned d[8], xw[8];
#pragma unroll
      for (int k = 0; k < 8; ++k) d[k] = cvt_pk_bf16(p[2 * k], p[2 * k + 1]);
#pragma unroll
      for (int k = 0; k < 8; ++k) xw[k] = __shfl_xor((int)d[k], 32);
      f0.u[0] = h32 ? xw[2] : d[0];
      f0.u[1] = h32 ? xw[3] : d[1];
      f0.u[2] = h32 ? d[2] : xw[0];
      f0.u[3] = h32 ? d[3] : xw[1];
      f1.u[0] = h32 ? xw[6] : d[4];
      f1.u[1] = h32 ? xw[7] : d[5];
      f1.u[2] = h32 ? d[6] : xw[4];
      f1.u[3] = h32 ? d[7] : xw[5];
    }
#endif
    // ---- O += V @ P ----
    __builtin_amdgcn_s_setprio(1);
    acc = __builtin_amdgcn_mfma_f32_32x32x16_bf16(va, f0.v, acc, 0, 0, 0);
    acc = __builtin_amdgcn_mfma_f32_32x32x16_bf16(vb, f1.v, acc, 0, 0, 0);
    __builtin_amdgcn_s_setprio(0);

    ka = kan;
    kb = kbn;
  }

  // ---- epilogue: finish l across halves, write O/l partials ----
  const size_t base = ((size_t)b * NH_ + hq) * N_;
  const float l = ps + __shfl_xor(ps, 32);
  const int jg = jt * 32 + j32;
  if (h32 == 0) LPart[base + jg] = l;
  short* OP = OPart + (base + jg) * 32;
#pragma unroll
  for (int g2 = 0; g2 < 4; ++g2) {  // regs 4g..4g+3 -> c = 8g + 4*h32 + 0..3
    bf16x4 o = {f2bf(acc[4 * g2 + 0]), f2bf(acc[4 * g2 + 1]),
                f2bf(acc[4 * g2 + 2]), f2bf(acc[4 * g2 + 3])};
    *(bf16x4*)(OP + 8 * g2 + 4 * h32) = o;
  }
}

// ---------------------------------------------------------------------------
// Kernel 3: merge 8 KV-eighth partials, normalize, out-proj, residual.
// Grid (64 n-blocks, 2 co-halves, 8 b) = 1024 blocks.
// out[b,co,n] = WoB @ (sum_h O_h / sum_h l_h) + x
// ---------------------------------------------------------------------------
__global__ __launch_bounds__(256) void out_proj(const short* __restrict__ OPart,
                                                const float* __restrict__ LPart,
                                                const short* __restrict__ WoB,
                                                const float* __restrict__ x,
                                                float* __restrict__ out) {
  const int b = blockIdx.z, chalf = blockIdx.y;
  const int tid = threadIdx.x;
  const int wave = tid >> 6, lane = tid & 63;
  const int col = lane & 15, quad = lane >> 4;
  const int jg = blockIdx.x * 64 + wave * 16 + col;  // global n/j
  const int n0 = blockIdx.x * 64 + wave * 16;

  float osum[8];
#pragma unroll
  for (int e = 0; e < 8; ++e) osum[e] = 0.f;
  float lsum = 0.f;
#pragma unroll
  for (int h = 0; h < NH_; ++h) {
    const size_t p = ((size_t)b * NH_ + h) * N_ + jg;
    const bf16x8 o = *(const bf16x8*)(OPart + p * 32 + quad * 8);
#pragma unroll
    for (int e = 0; e < 8; ++e) osum[e] += bf2f(o[e]);
    lsum += LPart[p];
  }
  const float linv = 1.f / lsum;
  bf16x8 bf;
#pragma unroll
  for (int e = 0; e < 8; ++e) bf[e] = f2bf(osum[e] * linv);

  const f32x4 z4 = {0.f, 0.f, 0.f, 0.f};
  const float* xb = x + (size_t)b * C_ * N_;
  float* ob = out + (size_t)b * C_ * N_;
#pragma unroll
  for (int ct = 0; ct < 8; ++ct) {
    const int ctg = chalf * 8 + ct;
    const bf16x8 af = *(const bf16x8*)(WoB + (ctg * 16 + col) * 32 + quad * 8);
    const f32x4 a = __builtin_amdgcn_mfma_f32_16x16x32_bf16(af, bf, z4, 0, 0, 0);
#pragma unroll
    for (int r = 0; r < 4; ++r) {
      const size_t idx = (size_t)(ctg * 16 + quad * 4 + r) * N_ + n0 + col;
      ob[idx] = a[r] + xb[idx];
    }
  }
}

// ---------------------------------------------------------------------------
extern "C" void kernel_launch(void* const* d_in, const int* in_sizes, int n_in,
                              void* d_out, int out_size, void* d_ws,
                              size_t ws_size, hipStream_t stream) {
  const float* x = (const float*)d_in[0];      // [8,256,64,64]
  const float* Wt = (const float*)d_in[1];     // [96,256]
  const float* Wo = (const float*)d_in[2];     // [256,32]
  const float* scale = (const float*)d_in[3];  // [1]
  float* out = (float*)d_out;

  // ws: OPart bf16 [8][8][4096][32] (16.8 MB) | LPart f32 [8][8][4096] (1 MB)
  //   | Kf (2 MB) | Qf (2 MB) | Vf (2 MB) | WtHi | WtLo | WoB  (~24 MB)
  short* OPart = (short*)d_ws;
  float* LPart = (float*)(OPart + (size_t)B_ * NH_ * N_ * 32);
  short* Kf = (short*)(LPart + (size_t)B_ * NH_ * N_);
  short* Qf = Kf + (size_t)B_ * 128 * 1024;
  short* Vf = Qf + (size_t)B_ * 128 * 1024;
  short* WtHi = Vf + (size_t)B_ * 256 * 512;
  short* WtLo = WtHi + 96 * C_;
  short* WoB = WtLo + 96 * C_;

  prep_weights<<<dim3(128), 256, 0, stream>>>(Wt, Wo, scale, WtHi, WtLo, WoB);
  qkv_mfma<<<dim3(64, B_), 256, 0, stream>>>(x, WtHi, WtLo, Kf, Qf, Vf);
  flash_attn<<<dim3(1024), 512, 0, stream>>>(Kf, Qf, Vf, OPart, LPart);
  out_proj<<<dim3(64, 2, B_), 256, 0, stream>>>(OPart, LPart, WoB, x, out);
}

// Round 12
// 150.317 us; speedup vs baseline: 1.0392x; 1.0026x over previous
//
#include <hip/hip_runtime.h>
#include <math.h>

// Problem constants: B=8, C=256, CR=32, N=4096 (=64*64)
#define B_ 8
#define C_ 256
#define CR_ 32
#define N_ 4096
#define NH_ 8  // KV split factor (eighths)

typedef __attribute__((ext_vector_type(8))) short bf16x8;   // MFMA A/B frag
typedef __attribute__((ext_vector_type(4))) short bf16x4;
typedef __attribute__((ext_vector_type(4))) float f32x4;    // 16x16 C/D frag
typedef __attribute__((ext_vector_type(16))) float f32x16;  // 32x32 C/D frag
typedef __attribute__((ext_vector_type(2))) unsigned uint32x2;

#if defined(__has_builtin)
#if __has_builtin(__builtin_amdgcn_permlane32_swap)
#define HAVE_PLSWAP 1
#endif
#endif

__device__ inline short f2bf(float f) {  // RTNE
  union { float f; unsigned u; } v; v.f = f;
  unsigned r = v.u + 0x7FFFu + ((v.u >> 16) & 1u);
  return (short)(r >> 16);
}
__device__ inline float bf2f(short h) {
  union { unsigned u; float f; } v; v.u = ((unsigned)(unsigned short)h) << 16;
  return v.f;
}
__device__ inline short f2bf_r(float f) {  // cheap round for hot paths
  return (short)((__float_as_uint(f) + 0x8000u) >> 16);
}

// pack 2 f32 -> 1 dword of 2 bf16 (low=a, high=b), single VALU op
__device__ inline unsigned cvt_pk_bf16(float a, float b) {
  unsigned d;
  asm("v_cvt_pk_bf16_f32 %0, %1, %2" : "=v"(d) : "v"(a), "v"(b));
  return d;
}

// ---------------------------------------------------------------------------
// FRAGMENT-MAJOR LAYOUTS (round-5, kept).
//   Kf[b][kt=0..127][ch=0..1][lane=0..63][e=0..7]  (A-frag: key=kt*32+(l&31),
//       c = ch*16 + (l>>5)*8 + e)
//   Qf[b][jt=0..127][ch=0..1][lane][e]             (B-frag: col=jt*32+(l&31),
//       c = ch*16 + (l>>5)*8 + e)
//   Vf[b][n16=0..255][lane][e]                     (A-frag: c=(l&31),
//       key = n16*16 + (l>>5)*8 + e)
// ROUND-12: R11 (LDS-only inner loop) stayed ~33us -> global-load latency
// exonerated.  Remaining wall: the PER-WAVE SERIAL CHAIN S->exp2->pack->PV
// (never pipelined intra-wave; '#pragma unroll 1' even forbade the
// compiler from overlapping tiles).  Fix: 2-stage software pipeline --
// each iteration issues S(t+1) on the MFMA pipe FIRST, then exp2/pack(t)
// on TRANS/VALU (hides S(t+1) latency under a tile of VALU work), then
// PV(t).  MFMA and VALU pipes are separate (m114): steady-state cost =
// max(softmax, MFMA) not their sum.  +16 VGPR (s_next) -> ~96 unified,
// still <=128 class; LDS 64KB caps at 2 blocks/CU = 4 waves/SIMD.
// Tripwire: WRITE_SIZE ~17.8MB; growth = spill.
// ---------------------------------------------------------------------------

// ---------------------------------------------------------------------------
// Kernel 0: weight prep.  WtHi/WtLo = split-bf16 of Wt (log2e folded into Q
// rows 32..63 so softmax runs in exp2 domain).  WoB = bf16(Wo * scale).
// ---------------------------------------------------------------------------
__global__ __launch_bounds__(256) void prep_weights(const float* __restrict__ Wt,
                                                    const float* __restrict__ Wo,
                                                    const float* __restrict__ scale,
                                                    short* __restrict__ WtHi,
                                                    short* __restrict__ WtLo,
                                                    short* __restrict__ WoB) {
  const int blk = blockIdx.x, tid = threadIdx.x;
  if (blk < 96) {
    float v = Wt[blk * C_ + tid];
    if (blk >= 32 && blk < 64) v *= 1.44269504f;  // log2(e) into Q
    const short h = f2bf(v);
    WtHi[blk * C_ + tid] = h;
    WtLo[blk * C_ + tid] = f2bf(v - bf2f(h));
  } else {
    const int idx = (blk - 96) * 256 + tid;
    WoB[idx] = f2bf(Wo[idx] * scale[0]);
  }
}

// ---------------------------------------------------------------------------
// Kernel 1: QKV projection, pure MFMA, no LDS, x prefetched one chunk ahead.
// Epilogue writes directly into fragment-major Kf/Qf/Vf (scattered 2B
// stores, paid once here instead of on every flash_attn fragment load).
// ---------------------------------------------------------------------------
__global__ __launch_bounds__(256) void qkv_mfma(const float* __restrict__ x,
                                                const short* __restrict__ WtHi,
                                                const short* __restrict__ WtLo,
                                                short* __restrict__ Kf,
                                                short* __restrict__ Qf,
                                                short* __restrict__ Vf) {
  const int b = blockIdx.y;
  const int tid = threadIdx.x;
  const int wave = tid >> 6, lane = tid & 63;
  const int col = lane & 15, quad = lane >> 4;
  const int n0 = (blockIdx.x * 4 + wave) * 16;

  const f32x4 z4 = {0.f, 0.f, 0.f, 0.f};
  f32x4 acc[6] = {z4, z4, z4, z4, z4, z4};  // 0..3 = KQ o-tiles, 4..5 = V

  const float* xb = x + (size_t)b * C_ * N_ + n0 + col;
  float xcur[8], xnxt[8];
#pragma unroll
  for (int j = 0; j < 8; ++j) xcur[j] = xb[(size_t)(quad * 8 + j) * N_];

#pragma unroll 2
  for (int c0 = 0; c0 < C_; c0 += 32) {
    if (c0 < C_ - 32) {
#pragma unroll
      for (int j = 0; j < 8; ++j)
        xnxt[j] = xb[(size_t)(c0 + 32 + quad * 8 + j) * N_];
    }
    bf16x8 xh, xl;
#pragma unroll
    for (int j = 0; j < 8; ++j) {
      const short h = (short)(__float_as_uint(xcur[j]) >> 16);  // trunc hi
      xh[j] = h;
      xl[j] = f2bf_r(xcur[j] - bf2f(h));
    }
#pragma unroll
    for (int ot = 0; ot < 4; ++ot) {  // K/Q: B-operand = Wt rows 0..63
      const int off = (ot * 16 + col) * C_ + c0 + quad * 8;
      const bf16x8 bh = *(const bf16x8*)(WtHi + off);
      const bf16x8 bl = *(const bf16x8*)(WtLo + off);
      acc[ot] = __builtin_amdgcn_mfma_f32_16x16x32_bf16(xh, bh, acc[ot], 0, 0, 0);
      acc[ot] = __builtin_amdgcn_mfma_f32_16x16x32_bf16(xl, bh, acc[ot], 0, 0, 0);
      acc[ot] = __builtin_amdgcn_mfma_f32_16x16x32_bf16(xh, bl, acc[ot], 0, 0, 0);
    }
#pragma unroll
    for (int ct = 0; ct < 2; ++ct) {  // V: A-operand = Wt rows 64..95
      const int off = ((64 + ct * 16) + col) * C_ + c0 + quad * 8;
      const bf16x8 ah = *(const bf16x8*)(WtHi + off);
      const bf16x8 al = *(const bf16x8*)(WtLo + off);
      acc[4 + ct] = __builtin_amdgcn_mfma_f32_16x16x32_bf16(ah, xh, acc[4 + ct], 0, 0, 0);
      acc[4 + ct] = __builtin_amdgcn_mfma_f32_16x16x32_bf16(ah, xl, acc[4 + ct], 0, 0, 0);
      acc[4 + ct] = __builtin_amdgcn_mfma_f32_16x16x32_bf16(al, xh, acc[4 + ct], 0, 0, 0);
    }
#pragma unroll
    for (int j = 0; j < 8; ++j) xcur[j] = xnxt[j];
  }

  // K epilogue (ot 0..1): D row=(quad*4+r)+n0 = key i, col-dim = c
#pragma unroll
  for (int ot = 0; ot < 2; ++ot)
#pragma unroll
    for (int r = 0; r < 4; ++r) {
      const int i = n0 + quad * 4 + r;
      const int c = ot * 16 + col;
      const int ln = (i & 31) | (((c >> 3) & 1) << 5);
      Kf[(((size_t)(b * 128 + (i >> 5)) * 2 + (c >> 4)) * 64 + ln) * 8 + (c & 7)] =
          f2bf(acc[ot][r]);
    }
  // Q epilogue (ot 2..3): col j = n, c = o-32
#pragma unroll
  for (int ot = 2; ot < 4; ++ot)
#pragma unroll
    for (int r = 0; r < 4; ++r) {
      const int j = n0 + quad * 4 + r;
      const int c = (ot - 2) * 16 + col;
      const int ln = (j & 31) | (((c >> 3) & 1) << 5);
      Qf[(((size_t)(b * 128 + (j >> 5)) * 2 + (c >> 4)) * 64 + ln) * 8 + (c & 7)] =
          f2bf(acc[ot][r]);
    }
  // V epilogue: c = ct*16+quad*4+r, key n = n0+col
#pragma unroll
  for (int ct = 0; ct < 2; ++ct)
#pragma unroll
    for (int r = 0; r < 4; ++r) {
      const int c = ct * 16 + quad * 4 + r;
      const int n = n0 + col;
      const int ln = c | (((n >> 3) & 1) << 5);
      Vf[((size_t)(b * 256 + (n >> 4)) * 64 + ln) * 8 + (n & 7)] =
          f2bf(acc[4 + ct][r]);
    }
}

// ---------------------------------------------------------------------------
// Kernel 2: 32x32-MFMA flash attention, LDS-staged K/V, 2-STAGE PIPELINE.
// Block = 512 threads = 8 waves; wave w owns j-tile jp*8+w; all waves share
// one KV-eighth staged in LDS (64 KB) once.  Per iteration:
//   1. issue S(t+1) MFMA (K frags already in regs)      [MFMA pipe]
//   2. refill K regs for tile t+2 from LDS              [DS, slack ~1 iter]
//   3. exp2/sum/pack/permlane on s(t)                   [TRANS+VALU,
//      hides S(t+1) MFMA latency]
//   4. PV(t)                                            [MFMA pipe]
// Steady state = max(softmax, MFMA) instead of serial sum.
// ---------------------------------------------------------------------------
__global__ __launch_bounds__(512) void flash_attn(const short* __restrict__ Kf,
                                                  const short* __restrict__ Qf,
                                                  const short* __restrict__ Vf,
                                                  short* __restrict__ OPart,
                                                  float* __restrict__ LPart) {
  __shared__ short Ks[16384];  // 16 k-tiles x 1024 shorts (2 KB) = 32 KB
  __shared__ short Vs[16384];  // 16 v-tiles x 1024 shorts = 32 KB

  const int bid = blockIdx.x;                 // 0..1023
  const int xcd = bid & 7, w = bid >> 3;      // w = 0..127
  const int g = xcd * 8 + (w >> 4);           // (b,hq) group 0..63, XCD-local
  const int b = g >> 3, hq = g & 7;
  const int jp = w & 15;                      // j-panel 0..15 (8 j-tiles)
  const int tid = threadIdx.x;
  const int wave = tid >> 6, lane = tid & 63;
  const int jt = jp * 8 + wave;               // this wave's j-tile 0..127
  const int j32 = lane & 31, h32 = lane >> 5;

  // ---- stage K/V eighth into LDS (coalesced 16B chunks, once) ----
  {
    const bf16x8* gK = (const bf16x8*)(Kf + ((size_t)(b * 128 + hq * 16) * 2) * 512);
    const bf16x8* gV = (const bf16x8*)(Vf + ((size_t)(b * 256 + hq * 32)) * 512);
    bf16x8* sK = (bf16x8*)Ks;
    bf16x8* sV = (bf16x8*)Vs;
#pragma unroll
    for (int i = 0; i < 4; ++i) {
      sK[tid + i * 512] = gK[tid + i * 512];
      sV[tid + i * 512] = gV[tid + i * 512];
    }
  }
  __syncthreads();

  const f32x16 z16 = {0.f};
  // Q B-frags, loop-invariant, coalesced from global
  const short* pQ = Qf + ((size_t)(b * 128 + jt) * 2) * 512 + lane * 8;
  const bf16x8 qf0 = *(const bf16x8*)(pQ);
  const bf16x8 qf1 = *(const bf16x8*)(pQ + 512);

  f32x16 acc = z16;
  float ps = 0.f;

  const short* sKl = Ks + lane * 8;
  const short* sVl = Vs + lane * 8;

  // ---- pipeline prologue: s_cur = S(tile 0); K regs <- tile 1 ----
  bf16x8 ka = *(const bf16x8*)(sKl);
  bf16x8 kb = *(const bf16x8*)(sKl + 512);
  f32x16 scur = __builtin_amdgcn_mfma_f32_32x32x16_bf16(ka, qf0, z16, 0, 0, 0);
  scur = __builtin_amdgcn_mfma_f32_32x32x16_bf16(kb, qf1, scur, 0, 0, 0);
  ka = *(const bf16x8*)(sKl + 1024);
  kb = *(const bf16x8*)(sKl + 1536);

#pragma unroll 1
  for (int t = 0; t < 16; ++t) {
    // ---- 1. issue S(t+1) on the MFMA pipe (t=15: dummy, discarded) ----
    __builtin_amdgcn_s_setprio(1);
    f32x16 snx = __builtin_amdgcn_mfma_f32_32x32x16_bf16(ka, qf0, z16, 0, 0, 0);
    snx = __builtin_amdgcn_mfma_f32_32x32x16_bf16(kb, qf1, snx, 0, 0, 0);
    __builtin_amdgcn_s_setprio(0);
    // ---- 2. refill K regs for tile t+2 (LDS; ~1 full iter of slack) ----
    const int tk = (t + 2) & 15;
    ka = *(const bf16x8*)(sKl + tk * 1024);
    kb = *(const bf16x8*)(sKl + tk * 1024 + 512);
    // V for THIS tile (LDS; needed after exp/pack)
    const bf16x8 va = *(const bf16x8*)(sVl + t * 1024);
    const bf16x8 vb = *(const bf16x8*)(sVl + t * 1024 + 512);
    // ---- 3. softmax on s(t) -- overlaps S(t+1) MFMA latency ----
    float p[16];
#pragma unroll
    for (int r = 0; r < 16; ++r) p[r] = __builtin_amdgcn_exp2f(scur[r]);
    ps += (((p[0] + p[1]) + (p[2] + p[3])) + ((p[4] + p[5]) + (p[6] + p[7]))) +
          (((p[8] + p[9]) + (p[10] + p[11])) + ((p[12] + p[13]) + (p[14] + p[15])));
    union { unsigned u[4]; bf16x8 v; } f0, f1;
#ifdef HAVE_PLSWAP
    {
      const unsigned d0 = cvt_pk_bf16(p[0], p[1]);
      const unsigned d1 = cvt_pk_bf16(p[2], p[3]);
      const unsigned d2 = cvt_pk_bf16(p[4], p[5]);
      const unsigned d3 = cvt_pk_bf16(p[6], p[7]);
      const uint32x2 r0 = __builtin_amdgcn_permlane32_swap(d0, d2, false, false);
      f0.u[0] = r0[0]; f0.u[2] = r0[1];
      const uint32x2 r1 = __builtin_amdgcn_permlane32_swap(d1, d3, false, false);
      f0.u[1] = r1[0]; f0.u[3] = r1[1];
      const unsigned d4 = cvt_pk_bf16(p[8], p[9]);
      const unsigned d5 = cvt_pk_bf16(p[10], p[11]);
      const unsigned d6 = cvt_pk_bf16(p[12], p[13]);
      const unsigned d7 = cvt_pk_bf16(p[14], p[15]);
      const uint32x2 r2 = __builtin_amdgcn_permlane32_swap(d4, d6, false, false);
      f1.u[0] = r2[0]; f1.u[2] = r2[1];
      const uint32x2 r3 = __builtin_amdgcn_permlane32_swap(d5, d7, false, false);
      f1.u[1] = r3[0]; f1.u[3] = r3[1];
    }
#else
    {
      unsigned d[8], xw[8];
#pragma unroll
      for (int k = 0; k < 8; ++k) d[k] = cvt_pk_bf16(p[2 * k], p[2 * k + 1]);
#pragma unroll
      for (int k = 0; k < 8; ++k) xw[k] = __shfl_xor((int)d[k], 32);
      f0.u[0] = h32 ? xw[2] : d[0];
      f0.u[1] = h32 ? xw[3] : d[1];
      f0.u[2] = h32 ? d[2] : xw[0];
      f0.u[3] = h32 ? d[3] : xw[1];
      f1.u[0] = h32 ? xw[6] : d[4];
      f1.u[1] = h32 ? xw[7] : d[5];
      f1.u[2] = h32 ? d[6] : xw[4];
      f1.u[3] = h32 ? d[7] : xw[5];
    }
#endif
    // ---- 4. PV(t) ----
    __builtin_amdgcn_s_setprio(1);
    acc = __builtin_amdgcn_mfma_f32_32x32x16_bf16(va, f0.v, acc, 0, 0, 0);
    acc = __builtin_amdgcn_mfma_f32_32x32x16_bf16(vb, f1.v, acc, 0, 0, 0);
    __builtin_amdgcn_s_setprio(0);

    scur = snx;
  }

  // ---- epilogue: finish l across halves, write O/l partials ----
  const size_t base = ((size_t)b * NH_ + hq) * N_;
  const float l = ps + __shfl_xor(ps, 32);
  const int jg = jt * 32 + j32;
  if (h32 == 0) LPart[base + jg] = l;
  short* OP = OPart + (base + jg) * 32;
#pragma unroll
  for (int g2 = 0; g2 < 4; ++g2) {  // regs 4g..4g+3 -> c = 8g + 4*h32 + 0..3
    bf16x4 o = {f2bf(acc[4 * g2 + 0]), f2bf(acc[4 * g2 + 1]),
                f2bf(acc[4 * g2 + 2]), f2bf(acc[4 * g2 + 3])};
    *(bf16x4*)(OP + 8 * g2 + 4 * h32) = o;
  }
}

// ---------------------------------------------------------------------------
// Kernel 3: merge 8 KV-eighth partials, normalize, out-proj, residual.
// Grid (64 n-blocks, 2 co-halves, 8 b) = 1024 blocks.
// out[b,co,n] = WoB @ (sum_h O_h / sum_h l_h) + x
// ---------------------------------------------------------------------------
__global__ __launch_bounds__(256) void out_proj(const short* __restrict__ OPart,
                                                const float* __restrict__ LPart,
                                                const short* __restrict__ WoB,
                                                const float* __restrict__ x,
                                                float* __restrict__ out) {
  const int b = blockIdx.z, chalf = blockIdx.y;
  const int tid = threadIdx.x;
  const int wave = tid >> 6, lane = tid & 63;
  const int col = lane & 15, quad = lane >> 4;
  const int jg = blockIdx.x * 64 + wave * 16 + col;  // global n/j
  const int n0 = blockIdx.x * 64 + wave * 16;

  float osum[8];
#pragma unroll
  for (int e = 0; e < 8; ++e) osum[e] = 0.f;
  float lsum = 0.f;
#pragma unroll
  for (int h = 0; h < NH_; ++h) {
    const size_t p = ((size_t)b * NH_ + h) * N_ + jg;
    const bf16x8 o = *(const bf16x8*)(OPart + p * 32 + quad * 8);
#pragma unroll
    for (int e = 0; e < 8; ++e) osum[e] += bf2f(o[e]);
    lsum += LPart[p];
  }
  const float linv = 1.f / lsum;
  bf16x8 bf;
#pragma unroll
  for (int e = 0; e < 8; ++e) bf[e] = f2bf(osum[e] * linv);

  const f32x4 z4 = {0.f, 0.f, 0.f, 0.f};
  const float* xb = x + (size_t)b * C_ * N_;
  float* ob = out + (size_t)b * C_ * N_;
#pragma unroll
  for (int ct = 0; ct < 8; ++ct) {
    const int ctg = chalf * 8 + ct;
    const bf16x8 af = *(const bf16x8*)(WoB + (ctg * 16 + col) * 32 + quad * 8);
    const f32x4 a = __builtin_amdgcn_mfma_f32_16x16x32_bf16(af, bf, z4, 0, 0, 0);
#pragma unroll
    for (int r = 0; r < 4; ++r) {
      const size_t idx = (size_t)(ctg * 16 + quad * 4 + r) * N_ + n0 + col;
      ob[idx] = a[r] + xb[idx];
    }
  }
}

// ---------------------------------------------------------------------------
extern "C" void kernel_launch(void* const* d_in, const int* in_sizes, int n_in,
                              void* d_out, int out_size, void* d_ws,
                              size_t ws_size, hipStream_t stream) {
  const float* x = (const float*)d_in[0];      // [8,256,64,64]
  const float* Wt = (const float*)d_in[1];     // [96,256]
  const float* Wo = (const float*)d_in[2];     // [256,32]
  const float* scale = (const float*)d_in[3];  // [1]
  float* out = (float*)d_out;

  // ws: OPart bf16 [8][8][4096][32] (16.8 MB) | LPart f32 [8][8][4096] (1 MB)
  //   | Kf (2 MB) | Qf (2 MB) | Vf (2 MB) | WtHi | WtLo | WoB  (~24 MB)
  short* OPart = (short*)d_ws;
  float* LPart = (float*)(OPart + (size_t)B_ * NH_ * N_ * 32);
  short* Kf = (short*)(LPart + (size_t)B_ * NH_ * N_);
  short* Qf = Kf + (size_t)B_ * 128 * 1024;
  short* Vf = Qf + (size_t)B_ * 128 * 1024;
  short* WtHi = Vf + (size_t)B_ * 256 * 512;
  short* WtLo = WtHi + 96 * C_;
  short* WoB = WtLo + 96 * C_;

  prep_weights<<<dim3(128), 256, 0, stream>>>(Wt, Wo, scale, WtHi, WtLo, WoB);
  qkv_mfma<<<dim3(64, B_), 256, 0, stream>>>(x, WtHi, WtLo, Kf, Qf, Vf);
  flash_attn<<<dim3(1024), 512, 0, stream>>>(Kf, Qf, Vf, OPart, LPart);
  out_proj<<<dim3(64, 2, B_), 256, 0, stream>>>(OPart, LPart, WoB, x, out);
}

// Round 13
// 147.868 us; speedup vs baseline: 1.0564x; 1.0166x over previous
//
#include <hip/hip_runtime.h>
#include <math.h>

// Problem constants: B=8, C=256, CR=32, N=4096 (=64*64)
#define B_ 8
#define C_ 256
#define CR_ 32
#define N_ 4096
#define NH_ 8  // KV split factor (eighths)

typedef __attribute__((ext_vector_type(8))) short bf16x8;   // MFMA A/B frag
typedef __attribute__((ext_vector_type(4))) short bf16x4;
typedef __attribute__((ext_vector_type(4))) float f32x4;    // 16x16 C/D frag
typedef __attribute__((ext_vector_type(16))) float f32x16;  // 32x32 C/D frag
typedef __attribute__((ext_vector_type(2))) unsigned uint32x2;

#if defined(__has_builtin)
#if __has_builtin(__builtin_amdgcn_permlane32_swap)
#define HAVE_PLSWAP 1
#endif
#endif

__device__ inline short f2bf(float f) {  // RTNE
  union { float f; unsigned u; } v; v.f = f;
  unsigned r = v.u + 0x7FFFu + ((v.u >> 16) & 1u);
  return (short)(r >> 16);
}
__device__ inline float bf2f(short h) {
  union { unsigned u; float f; } v; v.u = ((unsigned)(unsigned short)h) << 16;
  return v.f;
}
__device__ inline short f2bf_r(float f) {  // cheap round for hot paths
  return (short)((__float_as_uint(f) + 0x8000u) >> 16);
}

// pack 2 f32 -> 1 dword of 2 bf16 (low=a, high=b), single VALU op
__device__ inline unsigned cvt_pk_bf16(float a, float b) {
  unsigned d;
  asm("v_cvt_pk_bf16_f32 %0, %1, %2" : "=v"(d) : "v"(a), "v"(b));
  return d;
}

// ---------------------------------------------------------------------------
// FRAGMENT-MAJOR LAYOUTS (round-5, kept).
//   Kf[b][kt=0..127][ch=0..1][lane=0..63][e=0..7]  (A-frag: key=kt*32+(l&31),
//       c = ch*16 + (l>>5)*8 + e)
//   Qf[b][jt=0..127][ch=0..1][lane][e]             (B-frag: col=jt*32+(l&31),
//       c = ch*16 + (l>>5)*8 + e)
//   Vf[b][n16=0..255][lane][e]                     (A-frag: c=(l&31),
//       key = n16*16 + (l>>5)*8 + e)
// ROUND-13 = SETPRIO ABLATION.  R12's 2-stage pipeline was null -> the
// stall is not the intra-wave chain.  Per-SIMD cost is ~630 cyc/tile vs
// ~150-200 cyc issue content: waves behave as if they DON'T interleave.
// The one never-ablated mechanism that can serialize waves: s_setprio(1)
// around every MFMA pair (present since R0).  With identical loop bodies
// on all resident waves, constant priority toggling lets the scheduler
// persistently favor the in-MFMA wave and starve the rest (m190 measured
// setprio NEGATIVE on lockstep GEMM; its attn win was phase-diverse
// 1-wave blocks -- not our 8-wave shared-LDS block).  This round: remove
// ALL setprio from flash + allow 2x compiler unroll for cross-tile ILP.
// If null: flash is at its structural floor; out_proj/qkv are at BW
// roofline; fills are harness-fixed -> declare roofline next.
// ---------------------------------------------------------------------------

// ---------------------------------------------------------------------------
// Kernel 0: weight prep.  WtHi/WtLo = split-bf16 of Wt (log2e folded into Q
// rows 32..63 so softmax runs in exp2 domain).  WoB = bf16(Wo * scale).
// ---------------------------------------------------------------------------
__global__ __launch_bounds__(256) void prep_weights(const float* __restrict__ Wt,
                                                    const float* __restrict__ Wo,
                                                    const float* __restrict__ scale,
                                                    short* __restrict__ WtHi,
                                                    short* __restrict__ WtLo,
                                                    short* __restrict__ WoB) {
  const int blk = blockIdx.x, tid = threadIdx.x;
  if (blk < 96) {
    float v = Wt[blk * C_ + tid];
    if (blk >= 32 && blk < 64) v *= 1.44269504f;  // log2(e) into Q
    const short h = f2bf(v);
    WtHi[blk * C_ + tid] = h;
    WtLo[blk * C_ + tid] = f2bf(v - bf2f(h));
  } else {
    const int idx = (blk - 96) * 256 + tid;
    WoB[idx] = f2bf(Wo[idx] * scale[0]);
  }
}

// ---------------------------------------------------------------------------
// Kernel 1: QKV projection, pure MFMA, no LDS, x prefetched one chunk ahead.
// Epilogue writes directly into fragment-major Kf/Qf/Vf (scattered 2B
// stores, paid once here instead of on every flash_attn fragment load).
// ---------------------------------------------------------------------------
__global__ __launch_bounds__(256) void qkv_mfma(const float* __restrict__ x,
                                                const short* __restrict__ WtHi,
                                                const short* __restrict__ WtLo,
                                                short* __restrict__ Kf,
                                                short* __restrict__ Qf,
                                                short* __restrict__ Vf) {
  const int b = blockIdx.y;
  const int tid = threadIdx.x;
  const int wave = tid >> 6, lane = tid & 63;
  const int col = lane & 15, quad = lane >> 4;
  const int n0 = (blockIdx.x * 4 + wave) * 16;

  const f32x4 z4 = {0.f, 0.f, 0.f, 0.f};
  f32x4 acc[6] = {z4, z4, z4, z4, z4, z4};  // 0..3 = KQ o-tiles, 4..5 = V

  const float* xb = x + (size_t)b * C_ * N_ + n0 + col;
  float xcur[8], xnxt[8];
#pragma unroll
  for (int j = 0; j < 8; ++j) xcur[j] = xb[(size_t)(quad * 8 + j) * N_];

#pragma unroll 2
  for (int c0 = 0; c0 < C_; c0 += 32) {
    if (c0 < C_ - 32) {
#pragma unroll
      for (int j = 0; j < 8; ++j)
        xnxt[j] = xb[(size_t)(c0 + 32 + quad * 8 + j) * N_];
    }
    bf16x8 xh, xl;
#pragma unroll
    for (int j = 0; j < 8; ++j) {
      const short h = (short)(__float_as_uint(xcur[j]) >> 16);  // trunc hi
      xh[j] = h;
      xl[j] = f2bf_r(xcur[j] - bf2f(h));
    }
#pragma unroll
    for (int ot = 0; ot < 4; ++ot) {  // K/Q: B-operand = Wt rows 0..63
      const int off = (ot * 16 + col) * C_ + c0 + quad * 8;
      const bf16x8 bh = *(const bf16x8*)(WtHi + off);
      const bf16x8 bl = *(const bf16x8*)(WtLo + off);
      acc[ot] = __builtin_amdgcn_mfma_f32_16x16x32_bf16(xh, bh, acc[ot], 0, 0, 0);
      acc[ot] = __builtin_amdgcn_mfma_f32_16x16x32_bf16(xl, bh, acc[ot], 0, 0, 0);
      acc[ot] = __builtin_amdgcn_mfma_f32_16x16x32_bf16(xh, bl, acc[ot], 0, 0, 0);
    }
#pragma unroll
    for (int ct = 0; ct < 2; ++ct) {  // V: A-operand = Wt rows 64..95
      const int off = ((64 + ct * 16) + col) * C_ + c0 + quad * 8;
      const bf16x8 ah = *(const bf16x8*)(WtHi + off);
      const bf16x8 al = *(const bf16x8*)(WtLo + off);
      acc[4 + ct] = __builtin_amdgcn_mfma_f32_16x16x32_bf16(ah, xh, acc[4 + ct], 0, 0, 0);
      acc[4 + ct] = __builtin_amdgcn_mfma_f32_16x16x32_bf16(ah, xl, acc[4 + ct], 0, 0, 0);
      acc[4 + ct] = __builtin_amdgcn_mfma_f32_16x16x32_bf16(al, xh, acc[4 + ct], 0, 0, 0);
    }
#pragma unroll
    for (int j = 0; j < 8; ++j) xcur[j] = xnxt[j];
  }

  // K epilogue (ot 0..1): D row=(quad*4+r)+n0 = key i, col-dim = c
#pragma unroll
  for (int ot = 0; ot < 2; ++ot)
#pragma unroll
    for (int r = 0; r < 4; ++r) {
      const int i = n0 + quad * 4 + r;
      const int c = ot * 16 + col;
      const int ln = (i & 31) | (((c >> 3) & 1) << 5);
      Kf[(((size_t)(b * 128 + (i >> 5)) * 2 + (c >> 4)) * 64 + ln) * 8 + (c & 7)] =
          f2bf(acc[ot][r]);
    }
  // Q epilogue (ot 2..3): col j = n, c = o-32
#pragma unroll
  for (int ot = 2; ot < 4; ++ot)
#pragma unroll
    for (int r = 0; r < 4; ++r) {
      const int j = n0 + quad * 4 + r;
      const int c = (ot - 2) * 16 + col;
      const int ln = (j & 31) | (((c >> 3) & 1) << 5);
      Qf[(((size_t)(b * 128 + (j >> 5)) * 2 + (c >> 4)) * 64 + ln) * 8 + (c & 7)] =
          f2bf(acc[ot][r]);
    }
  // V epilogue: c = ct*16+quad*4+r, key n = n0+col
#pragma unroll
  for (int ct = 0; ct < 2; ++ct)
#pragma unroll
    for (int r = 0; r < 4; ++r) {
      const int c = ct * 16 + quad * 4 + r;
      const int n = n0 + col;
      const int ln = c | (((n >> 3) & 1) << 5);
      Vf[((size_t)(b * 256 + (n >> 4)) * 64 + ln) * 8 + (n & 7)] =
          f2bf(acc[4 + ct][r]);
    }
}

// ---------------------------------------------------------------------------
// Kernel 2: 32x32-MFMA flash attention, LDS-staged K/V, 2-stage pipeline,
// NO setprio (ablation), compiler 2x unroll for cross-tile ILP.
// Block = 512 threads = 8 waves; wave w owns j-tile jp*8+w; all waves share
// one KV-eighth staged in LDS (64 KB) once.
// ---------------------------------------------------------------------------
__global__ __launch_bounds__(512) void flash_attn(const short* __restrict__ Kf,
                                                  const short* __restrict__ Qf,
                                                  const short* __restrict__ Vf,
                                                  short* __restrict__ OPart,
                                                  float* __restrict__ LPart) {
  __shared__ short Ks[16384];  // 16 k-tiles x 1024 shorts (2 KB) = 32 KB
  __shared__ short Vs[16384];  // 16 v-tiles x 1024 shorts = 32 KB

  const int bid = blockIdx.x;                 // 0..1023
  const int xcd = bid & 7, w = bid >> 3;      // w = 0..127
  const int g = xcd * 8 + (w >> 4);           // (b,hq) group 0..63, XCD-local
  const int b = g >> 3, hq = g & 7;
  const int jp = w & 15;                      // j-panel 0..15 (8 j-tiles)
  const int tid = threadIdx.x;
  const int wave = tid >> 6, lane = tid & 63;
  const int jt = jp * 8 + wave;               // this wave's j-tile 0..127
  const int j32 = lane & 31, h32 = lane >> 5;

  // ---- stage K/V eighth into LDS (coalesced 16B chunks, once) ----
  {
    const bf16x8* gK = (const bf16x8*)(Kf + ((size_t)(b * 128 + hq * 16) * 2) * 512);
    const bf16x8* gV = (const bf16x8*)(Vf + ((size_t)(b * 256 + hq * 32)) * 512);
    bf16x8* sK = (bf16x8*)Ks;
    bf16x8* sV = (bf16x8*)Vs;
#pragma unroll
    for (int i = 0; i < 4; ++i) {
      sK[tid + i * 512] = gK[tid + i * 512];
      sV[tid + i * 512] = gV[tid + i * 512];
    }
  }
  __syncthreads();

  const f32x16 z16 = {0.f};
  // Q B-frags, loop-invariant, coalesced from global
  const short* pQ = Qf + ((size_t)(b * 128 + jt) * 2) * 512 + lane * 8;
  const bf16x8 qf0 = *(const bf16x8*)(pQ);
  const bf16x8 qf1 = *(const bf16x8*)(pQ + 512);

  f32x16 acc = z16;
  float ps = 0.f;

  const short* sKl = Ks + lane * 8;
  const short* sVl = Vs + lane * 8;

  // ---- pipeline prologue: s_cur = S(tile 0); K regs <- tile 1 ----
  bf16x8 ka = *(const bf16x8*)(sKl);
  bf16x8 kb = *(const bf16x8*)(sKl + 512);
  f32x16 scur = __builtin_amdgcn_mfma_f32_32x32x16_bf16(ka, qf0, z16, 0, 0, 0);
  scur = __builtin_amdgcn_mfma_f32_32x32x16_bf16(kb, qf1, scur, 0, 0, 0);
  ka = *(const bf16x8*)(sKl + 1024);
  kb = *(const bf16x8*)(sKl + 1536);

#pragma unroll 2
  for (int t = 0; t < 16; ++t) {
    // ---- 1. issue S(t+1) on the MFMA pipe (t=15: dummy, discarded) ----
    f32x16 snx = __builtin_amdgcn_mfma_f32_32x32x16_bf16(ka, qf0, z16, 0, 0, 0);
    snx = __builtin_amdgcn_mfma_f32_32x32x16_bf16(kb, qf1, snx, 0, 0, 0);
    // ---- 2. refill K regs for tile t+2 (LDS; ~1 full iter of slack) ----
    const int tk = (t + 2) & 15;
    ka = *(const bf16x8*)(sKl + tk * 1024);
    kb = *(const bf16x8*)(sKl + tk * 1024 + 512);
    // V for THIS tile (LDS; needed after exp/pack)
    const bf16x8 va = *(const bf16x8*)(sVl + t * 1024);
    const bf16x8 vb = *(const bf16x8*)(sVl + t * 1024 + 512);
    // ---- 3. softmax on s(t) -- overlaps S(t+1) MFMA latency ----
    float p[16];
#pragma unroll
    for (int r = 0; r < 16; ++r) p[r] = __builtin_amdgcn_exp2f(scur[r]);
    ps += (((p[0] + p[1]) + (p[2] + p[3])) + ((p[4] + p[5]) + (p[6] + p[7]))) +
          (((p[8] + p[9]) + (p[10] + p[11])) + ((p[12] + p[13]) + (p[14] + p[15])));
    union { unsigned u[4]; bf16x8 v; } f0, f1;
#ifdef HAVE_PLSWAP
    {
      const unsigned d0 = cvt_pk_bf16(p[0], p[1]);
      const unsigned d1 = cvt_pk_bf16(p[2], p[3]);
      const unsigned d2 = cvt_pk_bf16(p[4], p[5]);
      const unsigned d3 = cvt_pk_bf16(p[6], p[7]);
      const uint32x2 r0 = __builtin_amdgcn_permlane32_swap(d0, d2, false, false);
      f0.u[0] = r0[0]; f0.u[2] = r0[1];
      const uint32x2 r1 = __builtin_amdgcn_permlane32_swap(d1, d3, false, false);
      f0.u[1] = r1[0]; f0.u[3] = r1[1];
      const unsigned d4 = cvt_pk_bf16(p[8], p[9]);
      const unsigned d5 = cvt_pk_bf16(p[10], p[11]);
      const unsigned d6 = cvt_pk_bf16(p[12], p[13]);
      const unsigned d7 = cvt_pk_bf16(p[14], p[15]);
      const uint32x2 r2 = __builtin_amdgcn_permlane32_swap(d4, d6, false, false);
      f1.u[0] = r2[0]; f1.u[2] = r2[1];
      const uint32x2 r3 = __builtin_amdgcn_permlane32_swap(d5, d7, false, false);
      f1.u[1] = r3[0]; f1.u[3] = r3[1];
    }
#else
    {
      unsigned d[8], xw[8];
#pragma unroll
      for (int k = 0; k < 8; ++k) d[k] = cvt_pk_bf16(p[2 * k], p[2 * k + 1]);
#pragma unroll
      for (int k = 0; k < 8; ++k) xw[k] = __shfl_xor((int)d[k], 32);
      f0.u[0] = h32 ? xw[2] : d[0];
      f0.u[1] = h32 ? xw[3] : d[1];
      f0.u[2] = h32 ? d[2] : xw[0];
      f0.u[3] = h32 ? d[3] : xw[1];
      f1.u[0] = h32 ? xw[6] : d[4];
      f1.u[1] = h32 ? xw[7] : d[5];
      f1.u[2] = h32 ? d[6] : xw[4];
      f1.u[3] = h32 ? d[7] : xw[5];
    }
#endif
    // ---- 4. PV(t) ----
    acc = __builtin_amdgcn_mfma_f32_32x32x16_bf16(va, f0.v, acc, 0, 0, 0);
    acc = __builtin_amdgcn_mfma_f32_32x32x16_bf16(vb, f1.v, acc, 0, 0, 0);

    scur = snx;
  }

  // ---- epilogue: finish l across halves, write O/l partials ----
  const size_t base = ((size_t)b * NH_ + hq) * N_;
  const float l = ps + __shfl_xor(ps, 32);
  const int jg = jt * 32 + j32;
  if (h32 == 0) LPart[base + jg] = l;
  short* OP = OPart + (base + jg) * 32;
#pragma unroll
  for (int g2 = 0; g2 < 4; ++g2) {  // regs 4g..4g+3 -> c = 8g + 4*h32 + 0..3
    bf16x4 o = {f2bf(acc[4 * g2 + 0]), f2bf(acc[4 * g2 + 1]),
                f2bf(acc[4 * g2 + 2]), f2bf(acc[4 * g2 + 3])};
    *(bf16x4*)(OP + 8 * g2 + 4 * h32) = o;
  }
}

// ---------------------------------------------------------------------------
// Kernel 3: merge 8 KV-eighth partials, normalize, out-proj, residual.
// Grid (64 n-blocks, 2 co-halves, 8 b) = 1024 blocks.
// out[b,co,n] = WoB @ (sum_h O_h / sum_h l_h) + x
// ---------------------------------------------------------------------------
__global__ __launch_bounds__(256) void out_proj(const short* __restrict__ OPart,
                                                const float* __restrict__ LPart,
                                                const short* __restrict__ WoB,
                                                const float* __restrict__ x,
                                                float* __restrict__ out) {
  const int b = blockIdx.z, chalf = blockIdx.y;
  const int tid = threadIdx.x;
  const int wave = tid >> 6, lane = tid & 63;
  const int col = lane & 15, quad = lane >> 4;
  const int jg = blockIdx.x * 64 + wave * 16 + col;  // global n/j
  const int n0 = blockIdx.x * 64 + wave * 16;

  float osum[8];
#pragma unroll
  for (int e = 0; e < 8; ++e) osum[e] = 0.f;
  float lsum = 0.f;
#pragma unroll
  for (int h = 0; h < NH_; ++h) {
    const size_t p = ((size_t)b * NH_ + h) * N_ + jg;
    const bf16x8 o = *(const bf16x8*)(OPart + p * 32 + quad * 8);
#pragma unroll
    for (int e = 0; e < 8; ++e) osum[e] += bf2f(o[e]);
    lsum += LPart[p];
  }
  const float linv = 1.f / lsum;
  bf16x8 bf;
#pragma unroll
  for (int e = 0; e < 8; ++e) bf[e] = f2bf(osum[e] * linv);

  const f32x4 z4 = {0.f, 0.f, 0.f, 0.f};
  const float* xb = x + (size_t)b * C_ * N_;
  float* ob = out + (size_t)b * C_ * N_;
#pragma unroll
  for (int ct = 0; ct < 8; ++ct) {
    const int ctg = chalf * 8 + ct;
    const bf16x8 af = *(const bf16x8*)(WoB + (ctg * 16 + col) * 32 + quad * 8);
    const f32x4 a = __builtin_amdgcn_mfma_f32_16x16x32_bf16(af, bf, z4, 0, 0, 0);
#pragma unroll
    for (int r = 0; r < 4; ++r) {
      const size_t idx = (size_t)(ctg * 16 + quad * 4 + r) * N_ + n0 + col;
      ob[idx] = a[r] + xb[idx];
    }
  }
}

// ---------------------------------------------------------------------------
extern "C" void kernel_launch(void* const* d_in, const int* in_sizes, int n_in,
                              void* d_out, int out_size, void* d_ws,
                              size_t ws_size, hipStream_t stream) {
  const float* x = (const float*)d_in[0];      // [8,256,64,64]
  const float* Wt = (const float*)d_in[1];     // [96,256]
  const float* Wo = (const float*)d_in[2];     // [256,32]
  const float* scale = (const float*)d_in[3];  // [1]
  float* out = (float*)d_out;

  // ws: OPart bf16 [8][8][4096][32] (16.8 MB) | LPart f32 [8][8][4096] (1 MB)
  //   | Kf (2 MB) | Qf (2 MB) | Vf (2 MB) | WtHi | WtLo | WoB  (~24 MB)
  short* OPart = (short*)d_ws;
  float* LPart = (float*)(OPart + (size_t)B_ * NH_ * N_ * 32);
  short* Kf = (short*)(LPart + (size_t)B_ * NH_ * N_);
  short* Qf = Kf + (size_t)B_ * 128 * 1024;
  short* Vf = Qf + (size_t)B_ * 128 * 1024;
  short* WtHi = Vf + (size_t)B_ * 256 * 512;
  short* WtLo = WtHi + 96 * C_;
  short* WoB = WtLo + 96 * C_;

  prep_weights<<<dim3(128), 256, 0, stream>>>(Wt, Wo, scale, WtHi, WtLo, WoB);
  qkv_mfma<<<dim3(64, B_), 256, 0, stream>>>(x, WtHi, WtLo, Kf, Qf, Vf);
  flash_attn<<<dim3(1024), 512, 0, stream>>>(Kf, Qf, Vf, OPart, LPart);
  out_proj<<<dim3(64, 2, B_), 256, 0, stream>>>(OPart, LPart, WoB, x, out);
}